// Round 8
// baseline (297.559 us; speedup 1.0000x reference)
//
#include <hip/hip_runtime.h>
#include <stdint.h>

// GaitnetActor B=8192, OPT=16. Round 8: M=128 rows/block (8 batch elems),
// 1024 threads (16 waves), 1 block/CU, grid 1024. Wave tiles M64xN32 (2:1
// MFMA:LDS-read). M-half wave pairs load identical weight fragments -> L1
// hits halve L2 weight traffic. LDS 147.5 KB. bf16 MFMA / fp32 accum.
// out[0:131072]=logits fp32, [131072:262144]=duration fp32.

static constexpr int B_ = 8192;

typedef __attribute__((ext_vector_type(8))) short bf16x8;
typedef __attribute__((ext_vector_type(4))) float f32x4;

__device__ __forceinline__ float u2f(uint16_t u) {
    union { uint32_t i; float f; } c; c.i = (uint32_t)u << 16; return c.f;
}
__device__ __forceinline__ uint16_t f2u(float f) {
    union { float f; uint32_t i; } c; c.f = f;
    uint32_t x = c.i;
    return (uint16_t)((x + 0x7FFFu + ((x >> 16) & 1u)) >> 16);
}

// ws elem offsets (uint16): tw1 512x384, tw2 256x512, uw2 128x128, sw2 256x256
static constexpr int WTW1 = 0;
static constexpr int WTW2 = 196608;
static constexpr int WUW2 = 327680;
static constexpr int WSW2 = 344064;
static constexpr int WTOT = 409600;

__global__ __launch_bounds__(256) void k_conv(
    const float* __restrict__ tw1, const float* __restrict__ tw2,
    const float* __restrict__ uw2, const float* __restrict__ sw2,
    uint16_t* __restrict__ ws)
{
    int i = (blockIdx.x * 256 + threadIdx.x) * 4;
    const float* src;
    if (i < WTW2)      src = tw1 + i;
    else if (i < WUW2) src = tw2 + (i - WTW2);
    else if (i < WSW2) src = uw2 + (i - WUW2);
    else               src = sw2 + (i - WSW2);
    float4 v = *reinterpret_cast<const float4*>(src);
    ushort4 o;
    o.x = f2u(v.x); o.y = f2u(v.y); o.z = f2u(v.z); o.w = f2u(v.w);
    *reinterpret_cast<ushort4*>(ws + i) = o;
}

// LDS layout (bytes), all 16B-aligned.
static constexpr int OBS_OFF  = 0;       // float [8][152]  = 4864
static constexpr int NOOP_OFF = 4864;    // float [128]     = 512
static constexpr int H1S_OFF  = 5376;    // bf16  [8][264]  = 4224
static constexpr int SEB_OFF  = 9600;    // bf16  [8][264]  = 4224
static constexpr int H1U_OFF  = 13824;   // bf16  [128][136]= 34816
static constexpr int UET_OFF  = 48640;   // bf16  [128][136]= 34816
static constexpr int H1T_OFF  = 83456;   // bf16  [128][264]= 67584 (N-chunk 256)
static constexpr int T2_OFF   = H1T_OFF; // bf16  [128][264] (overlay after main)
static constexpr int SMEM_SZ  = 151040;  // 147.5 KB -> 1 block/CU

__global__ __launch_bounds__(1024) void k_main(
    const float* __restrict__ obs,
    const float* __restrict__ sw1, const float* __restrict__ sb1,
    const float* __restrict__ sb2,
    const float* __restrict__ uw1, const float* __restrict__ ub1,
    const float* __restrict__ ub2, const float* __restrict__ emb,
    const float* __restrict__ tb1, const float* __restrict__ tb2,
    const float* __restrict__ vw,  const float* __restrict__ vb,
    const float* __restrict__ dw,  const float* __restrict__ db,
    const uint16_t* __restrict__ wsb,
    float* __restrict__ out)
{
    __shared__ __align__(16) char smem[SMEM_SZ];
    float*    obsl  = (float*)(smem + OBS_OFF);
    float*    noopf = (float*)(smem + NOOP_OFF);
    uint16_t* h1s   = (uint16_t*)(smem + H1S_OFF);
    uint16_t* seb   = (uint16_t*)(smem + SEB_OFF);
    uint16_t* h1u   = (uint16_t*)(smem + H1U_OFF);
    uint16_t* uet   = (uint16_t*)(smem + UET_OFF);
    uint16_t* h1t   = (uint16_t*)(smem + H1T_OFF);
    uint16_t* t2    = (uint16_t*)(smem + T2_OFF);

    const int t    = threadIdx.x;
    const int wv   = t >> 6;        // 0..15
    const int lane = t & 63;
    const int quad = lane >> 4;
    const int l16  = lane & 15;
    const int b0   = blockIdx.x * 8;

    const int mh = wv >> 3;         // M-half (0..1) for main loop
    const int ng = wv & 7;          // N-group of 32 (0..7) for main loop

    const uint16_t* tw1b = wsb + WTW1;
    const uint16_t* tw2b = wsb + WTW2;
    const uint16_t* uw2b = wsb + WUW2;
    const uint16_t* sw2b = wsb + WSW2;

    // ---- stage 1: load 8 obs rows, uniq cols shifted +2 for alignment ----
    for (int i = t; i < 1200; i += 1024) {
        int e = i / 150, c = i - e * 150;
        int dst = (c < 22) ? c : c + 2;
        obsl[e * 152 + dst] = obs[(size_t)(b0 + e) * 150 + c];
    }
    __syncthreads();

    // ---- stage 2: small layer-1s (VALU) + noop flags ----
    if (t < 128) {
        int e = t >> 4, o = t & 15;
        noopf[t] = (obsl[e * 152 + 24 + o * 8] == 1.0f) ? 1.0f : 0.0f;
    }
    {   // shared L1: 8 elems x 256 neurons (2 per thread)
        const int n = t & 255;
        float w[22];
        #pragma unroll
        for (int k = 0; k < 22; ++k) w[k] = sw1[n * 22 + k];
        const float bias = sb1[n];
        #pragma unroll
        for (int ii = 0; ii < 2; ++ii) {
            int e = (t >> 8) + 4 * ii;
            const float2* xp = (const float2*)&obsl[e * 152];
            float a = bias;
            #pragma unroll
            for (int k = 0; k < 11; ++k) {
                float2 x2 = xp[k];
                a += w[2 * k] * x2.x + w[2 * k + 1] * x2.y;
            }
            h1s[e * 264 + n] = f2u(fmaxf(a, 0.f));
        }
    }
    {   // unique L1: 128 rows x 128 neurons (16 per thread)
        const int n = t & 127;
        float w[8];
        #pragma unroll
        for (int k = 0; k < 8; ++k) w[k] = uw1[n * 8 + k];
        const float bias = ub1[n];
        #pragma unroll
        for (int ii = 0; ii < 16; ++ii) {
            int row = (t >> 7) + 8 * ii;
            const float4* xp = (const float4*)&obsl[(row >> 4) * 152 + 24 + (row & 15) * 8];
            float4 xa = xp[0], xb = xp[1];
            float a = bias + w[0] * xa.x + w[1] * xa.y + w[2] * xa.z + w[3] * xa.w
                           + w[4] * xb.x + w[5] * xb.y + w[6] * xb.z + w[7] * xb.w;
            h1u[row * 136 + n] = f2u(fmaxf(a, 0.f));
        }
    }
    __syncthreads();

    // ---- stage 3 (wave-specialized) ----
    if (wv < 8) {
        // unique L2: waves 0-7 = (2 Mhalf x 4 Ngroup32), K=128 -> uet
        const int mhu = wv >> 2, ngu = wv & 3;
        f32x4 acc[4][2];
        float ev[2];
        #pragma unroll
        for (int nt = 0; nt < 2; ++nt) {
            int n = ngu * 32 + nt * 16 + l16;
            float bv = ub2[n];
            ev[nt] = emb[n];
            #pragma unroll
            for (int mt = 0; mt < 4; ++mt) acc[mt][nt] = {bv, bv, bv, bv};
        }
        #pragma unroll
        for (int kk = 0; kk < 4; ++kk) {
            bf16x8 bfr[2];
            #pragma unroll
            for (int nt = 0; nt < 2; ++nt)
                bfr[nt] = *reinterpret_cast<const bf16x8*>(
                    &uw2b[(ngu * 32 + nt * 16 + l16) * 128 + kk * 32 + quad * 8]);
            bf16x8 af[4];
            #pragma unroll
            for (int mt = 0; mt < 4; ++mt)
                af[mt] = *reinterpret_cast<const bf16x8*>(
                    &h1u[(mhu * 64 + mt * 16 + l16) * 136 + kk * 32 + quad * 8]);
            #pragma unroll
            for (int mt = 0; mt < 4; ++mt)
                #pragma unroll
                for (int nt = 0; nt < 2; ++nt)
                    acc[mt][nt] = __builtin_amdgcn_mfma_f32_16x16x32_bf16(
                        af[mt], bfr[nt], acc[mt][nt], 0, 0, 0);
        }
        #pragma unroll
        for (int mt = 0; mt < 4; ++mt)
            #pragma unroll
            for (int nt = 0; nt < 2; ++nt)
                #pragma unroll
                for (int r = 0; r < 4; ++r) {
                    int row = mhu * 64 + mt * 16 + quad * 4 + r;
                    float v = (noopf[row] != 0.0f) ? ev[nt] : fmaxf(acc[mt][nt][r], 0.f);
                    uet[row * 136 + ngu * 32 + nt * 16 + l16] = f2u(v);
                }
    } else {
        // shared L2: waves 8-15, each N=32 (nt=2), M rows 0..7 valid, K=256
        const int w8 = wv - 8;
        f32x4 acc[2];
        #pragma unroll
        for (int nt = 0; nt < 2; ++nt) {
            float bv = sb2[w8 * 32 + nt * 16 + l16];
            acc[nt] = {bv, bv, bv, bv};
        }
        const uint16_t* arow = &h1s[l16 * 264 + quad * 8];  // l16>=8: finite junk
        #pragma unroll
        for (int kk = 0; kk < 8; ++kk) {
            bf16x8 af = *reinterpret_cast<const bf16x8*>(arow + kk * 32);
            #pragma unroll
            for (int nt = 0; nt < 2; ++nt) {
                bf16x8 bf = *reinterpret_cast<const bf16x8*>(
                    &sw2b[(w8 * 32 + nt * 16 + l16) * 256 + kk * 32 + quad * 8]);
                acc[nt] = __builtin_amdgcn_mfma_f32_16x16x32_bf16(af, bf, acc[nt], 0, 0, 0);
            }
        }
        if (quad < 2) {                        // rows 0..7 valid
            #pragma unroll
            for (int nt = 0; nt < 2; ++nt)
                #pragma unroll
                for (int r = 0; r < 4; ++r)
                    seb[(quad * 4 + r) * 264 + w8 * 32 + nt * 16 + l16] =
                        f2u(fmaxf(acc[nt][r], 0.f));
        }
    }
    __syncthreads();

    // ---- stages 4/5 fused: 2 N-chunks of 256 trunk-L1 neurons ----
    f32x4 acc2[4][2];                           // trunk L2: M=64 x N=32 / wave
    #pragma unroll
    for (int nt = 0; nt < 2; ++nt) {
        float bv = tb2[ng * 32 + nt * 16 + l16];
        #pragma unroll
        for (int mt = 0; mt < 4; ++mt) acc2[mt][nt] = {bv, bv, bv, bv};
    }

    #pragma unroll
    for (int nc = 0; nc < 2; ++nc) {
        // ---- L1 chunk: M=128 x N=256, K=384; wave = Mhalf64 x N32 ----
        {
            f32x4 acc1[4][2];
            #pragma unroll
            for (int nt = 0; nt < 2; ++nt) {
                float bv = tb1[nc * 256 + ng * 32 + nt * 16 + l16];
                #pragma unroll
                for (int mt = 0; mt < 4; ++mt) acc1[mt][nt] = {bv, bv, bv, bv};
            }
            const uint16_t* bb = tw1b + (nc * 256 + ng * 32 + l16) * 384 + quad * 8;
            bf16x8 bc[2], bn[2];
            bc[0] = *reinterpret_cast<const bf16x8*>(bb);
            bc[1] = *reinterpret_cast<const bf16x8*>(bb + 6144);
            #pragma unroll
            for (int kk = 0; kk < 12; ++kk) {
                if (kk < 11) {
                    bn[0] = *reinterpret_cast<const bf16x8*>(bb + (kk + 1) * 32);
                    bn[1] = *reinterpret_cast<const bf16x8*>(bb + 6144 + (kk + 1) * 32);
                }
                bf16x8 af[4];
                if (kk < 8) {                   // A = seb broadcast (e = mh*4+mt)
                    #pragma unroll
                    for (int mt = 0; mt < 4; ++mt)
                        af[mt] = *reinterpret_cast<const bf16x8*>(
                            &seb[(mh * 4 + mt) * 264 + kk * 32 + quad * 8]);
                } else {                        // A = uet rows
                    #pragma unroll
                    for (int mt = 0; mt < 4; ++mt)
                        af[mt] = *reinterpret_cast<const bf16x8*>(
                            &uet[(mh * 64 + mt * 16 + l16) * 136 +
                                 (kk - 8) * 32 + quad * 8]);
                }
                #pragma unroll
                for (int mt = 0; mt < 4; ++mt)
                    #pragma unroll
                    for (int nt = 0; nt < 2; ++nt)
                        acc1[mt][nt] = __builtin_amdgcn_mfma_f32_16x16x32_bf16(
                            af[mt], bc[nt], acc1[mt][nt], 0, 0, 0);
                bc[0] = bn[0]; bc[1] = bn[1];
            }
            #pragma unroll
            for (int mt = 0; mt < 4; ++mt)
                #pragma unroll
                for (int nt = 0; nt < 2; ++nt)
                    #pragma unroll
                    for (int r = 0; r < 4; ++r) {
                        int row = mh * 64 + mt * 16 + quad * 4 + r;
                        h1t[row * 264 + ng * 32 + nt * 16 + l16] =
                            f2u(fmaxf(acc1[mt][nt][r], 0.f));
                    }
        }
        __syncthreads();                        // h1t chunk ready
        // ---- L2 accumulate: K-chunk of 256; wave = Mhalf64 x N32 ----
        {
            const uint16_t* cb = tw2b + (ng * 32 + l16) * 512 + nc * 256 + quad * 8;
            bf16x8 cc[2], cn[2];
            cc[0] = *reinterpret_cast<const bf16x8*>(cb);
            cc[1] = *reinterpret_cast<const bf16x8*>(cb + 8192);
            #pragma unroll
            for (int k2 = 0; k2 < 8; ++k2) {
                if (k2 < 7) {
                    cn[0] = *reinterpret_cast<const bf16x8*>(cb + (k2 + 1) * 32);
                    cn[1] = *reinterpret_cast<const bf16x8*>(cb + 8192 + (k2 + 1) * 32);
                }
                bf16x8 af[4];
                #pragma unroll
                for (int mt = 0; mt < 4; ++mt)
                    af[mt] = *reinterpret_cast<const bf16x8*>(
                        &h1t[(mh * 64 + mt * 16 + l16) * 264 + k2 * 32 + quad * 8]);
                #pragma unroll
                for (int mt = 0; mt < 4; ++mt)
                    #pragma unroll
                    for (int nt = 0; nt < 2; ++nt)
                        acc2[mt][nt] = __builtin_amdgcn_mfma_f32_16x16x32_bf16(
                            af[mt], cc[nt], acc2[mt][nt], 0, 0, 0);
                cc[0] = cn[0]; cc[1] = cn[1];
            }
        }
        if (nc == 0) __syncthreads();           // h1t consumed before overwrite
    }
    __syncthreads();                            // all h1t reads done
    // ---- t2 epilogue (overlays h1t) ----
    #pragma unroll
    for (int mt = 0; mt < 4; ++mt)
        #pragma unroll
        for (int nt = 0; nt < 2; ++nt)
            #pragma unroll
            for (int r = 0; r < 4; ++r) {
                int row = mh * 64 + mt * 16 + quad * 4 + r;
                t2[row * 264 + ng * 32 + nt * 16 + l16] =
                    f2u(fmaxf(acc2[mt][nt][r], 0.f));
            }
    __syncthreads();

    // ---- heads: wave wv does rows 8wv..8wv+7 ----
    {
        float vwf[4], dwf[4];
        #pragma unroll
        for (int j = 0; j < 4; ++j) {
            vwf[j] = vw[lane + 64 * j];
            dwf[j] = dw[lane + 64 * j];
        }
        const float vbf = vb[0], dbf = db[0];
        #pragma unroll
        for (int rr = 0; rr < 8; ++rr) {
            int row = wv * 8 + rr;
            float sv = 0.f, sd = 0.f;
            #pragma unroll
            for (int j = 0; j < 4; ++j) {
                float tv = u2f(t2[row * 264 + lane + 64 * j]);
                sv += tv * vwf[j];
                sd += tv * dwf[j];
            }
            #pragma unroll
            for (int off = 32; off > 0; off >>= 1) {
                sv += __shfl_down(sv, off);
                sd += __shfl_down(sd, off);
            }
            if (lane == 0) {
                int g = blockIdx.x * 128 + row;
                out[g] = sv + vbf;
                float z = sd + dbf;
                float sig = 1.f / (1.f + __expf(-z));
                out[B_ * 16 + g] = sig * 0.4f + 0.1f;
            }
        }
    }
}

extern "C" void kernel_launch(void* const* d_in, const int* in_sizes, int n_in,
                              void* d_out, int out_size, void* d_ws, size_t ws_size,
                              hipStream_t stream) {
    const float* obs = (const float*)d_in[0];
    const float* sw1 = (const float*)d_in[1];
    const float* sb1 = (const float*)d_in[2];
    const float* sw2 = (const float*)d_in[3];
    const float* sb2 = (const float*)d_in[4];
    const float* uw1 = (const float*)d_in[5];
    const float* ub1 = (const float*)d_in[6];
    const float* uw2 = (const float*)d_in[7];
    const float* ub2 = (const float*)d_in[8];
    const float* emb = (const float*)d_in[9];
    const float* tw1 = (const float*)d_in[10];
    const float* tb1 = (const float*)d_in[11];
    const float* tw2 = (const float*)d_in[12];
    const float* tb2 = (const float*)d_in[13];
    const float* vw  = (const float*)d_in[14];
    const float* vb  = (const float*)d_in[15];
    const float* dw  = (const float*)d_in[16];
    const float* db  = (const float*)d_in[17];

    uint16_t* wsb = (uint16_t*)d_ws;

    k_conv<<<WTOT / 1024, 256, 0, stream>>>(tw1, tw2, uw2, sw2, wsb);
    k_main<<<B_ / 8, 1024, 0, stream>>>(obs, sw1, sb1, sb2, uw1, ub1, ub2, emb,
                                        tb1, tb2, vw, vb, dw, db, wsb,
                                        (float*)d_out);
}